// Round 2
// baseline (4440.769 us; speedup 1.0000x reference)
//
#include <hip/hip_runtime.h>

#define N_NODES_C 100000
#define N_EDGES_C 1200000

// ---- degree histogram over row (edge_index arrives as int32 from the harness) ----
__global__ void deg_kernel(const int* __restrict__ ei, float* __restrict__ deg, int nedges) {
    int e = blockIdx.x * blockDim.x + threadIdx.x;
    if (e >= nedges) return;
    atomicAdd(deg + ei[e], 1.0f);
}

// ---- deg -> deg_inv_sqrt, in place ----
__global__ void deg_to_dis(float* __restrict__ deg, int n) {
    int i = blockIdx.x * blockDim.x + threadIdx.x;
    if (i >= n) return;
    float d = deg[i];
    deg[i] = (d > 0.f) ? (1.0f / sqrtf(fmaxf(d, 1.f))) : 0.f;
}

// ---- per-edge norm weight, Laplacian minus sign folded in ----
__global__ void norm_kernel(const int* __restrict__ ei, const float* __restrict__ dis,
                            float* __restrict__ nw, int nedges) {
    int e = blockIdx.x * blockDim.x + threadIdx.x;
    if (e >= nedges) return;
    nw[e] = -dis[ei[e]] * dis[ei[nedges + e]];
}

// ---- prop(t)[row] += nw * t[col], 16 threads/edge, float4 per thread ----
__global__ void prop_scatter(const float* __restrict__ t, const int* __restrict__ ei,
                             const float* __restrict__ nw, float* __restrict__ out,
                             int nedges) {
    int tid = blockIdx.x * blockDim.x + threadIdx.x;
    int e = tid >> 4;
    if (e >= nedges) return;
    int lane = tid & 15;
    int r = ei[e];
    int c = ei[nedges + e];
    float w = nw[e];
    float4 v = ((const float4*)(t + (size_t)c * 64))[lane];
    float* o = out + (size_t)r * 64 + lane * 4;
    atomicAdd(o + 0, w * v.x);
    atomicAdd(o + 1, w * v.y);
    atomicAdd(o + 2, w * v.z);
    atomicAdd(o + 3, w * v.w);
}

// ---- fused 3-term matmul: out = Tx0@W0 + Tx1@W1 + (2*t2p - Tx0)@W2 + b ----
template <int OUTC, bool RELU>
__global__ __launch_bounds__(256) void cheb_mm(const float* __restrict__ t0,
                                               const float* __restrict__ t1,
                                               const float* __restrict__ t2p,
                                               const float* __restrict__ W,  // [3,64,OUTC]
                                               const float* __restrict__ bias,
                                               float* __restrict__ out, int nnodes) {
    constexpr int NPB = 256 / OUTC;
    __shared__ float sW[3 * 64 * OUTC];
    __shared__ float s0[NPB][64];
    __shared__ float s1[NPB][64];
    __shared__ float s2[NPB][64];
    int tid = threadIdx.x;
    for (int i = tid; i < 3 * 64 * OUTC; i += 256) sW[i] = W[i];
    int node0 = blockIdx.x * NPB;
    for (int i = tid; i < NPB * 64; i += 256) {
        int ln = i >> 6;
        int k = i & 63;
        int n = node0 + ln;
        float a0 = 0.f, a1 = 0.f, a2 = 0.f;
        if (n < nnodes) {
            size_t idx = (size_t)n * 64 + k;
            a0 = t0[idx];
            a1 = t1[idx];
            a2 = 2.0f * t2p[idx] - a0;
        }
        s0[ln][k] = a0;
        s1[ln][k] = a1;
        s2[ln][k] = a2;
    }
    __syncthreads();
    int ln = tid / OUTC;
    int c = tid % OUTC;
    int n = node0 + ln;
    if (n >= nnodes) return;
    float acc = bias[c];
#pragma unroll
    for (int k = 0; k < 64; ++k) {
        acc += s0[ln][k] * sW[(0 * 64 + k) * OUTC + c];
        acc += s1[ln][k] * sW[(1 * 64 + k) * OUTC + c];
        acc += s2[ln][k] * sW[(2 * 64 + k) * OUTC + c];
    }
    if (RELU) acc = fmaxf(acc, 0.f);
    out[(size_t)n * OUTC + c] = acc;
}

extern "C" void kernel_launch(void* const* d_in, const int* in_sizes, int n_in,
                              void* d_out, int out_size, void* d_ws, size_t ws_size,
                              hipStream_t stream) {
    const float* x  = (const float*)d_in[0];
    const int*   ei = (const int*)d_in[1];   // harness uploads integer inputs as int32
    const float* W1 = (const float*)d_in[2];
    const float* b1 = (const float*)d_in[3];
    const float* W2 = (const float*)d_in[4];
    const float* b2 = (const float*)d_in[5];
    float* out = (float*)d_out;

    const int NN = N_NODES_C;
    const int NE = N_EDGES_C;
    const size_t FEAT_BYTES = (size_t)NN * 64 * sizeof(float);

    char* ws = (char*)d_ws;
    size_t off = 0;
    auto alloc = [&](size_t bytes) -> void* {
        void* p = ws + off;
        off += (bytes + 255) & ~(size_t)255;
        return p;
    };
    float* deg = (float*)alloc((size_t)NN * 4);   // becomes deg_inv_sqrt in place
    float* nw  = (float*)alloc((size_t)NE * 4);
    float* T1  = (float*)alloc(FEAT_BYTES);
    float* T2  = (float*)alloc(FEAT_BYTES);
    float* H   = (float*)alloc(FEAT_BYTES);

    const int EB = (NE + 255) / 256;          // per-edge 1-thread kernels
    const int PB = (NE * 16 + 255) / 256;     // prop: 16 threads/edge
    const int NB = (NN + 255) / 256;

    // ---- graph normalization ----
    hipMemsetAsync(deg, 0, (size_t)NN * 4, stream);
    deg_kernel<<<EB, 256, 0, stream>>>(ei, deg, NE);
    deg_to_dis<<<NB, 256, 0, stream>>>(deg, NN);
    norm_kernel<<<EB, 256, 0, stream>>>(ei, deg, nw, NE);

    // ---- layer 1: H = relu(x@W1_0 + T1@W1_1 + (2*T2 - x)@W1_2 + b1) ----
    hipMemsetAsync(T1, 0, FEAT_BYTES, stream);
    prop_scatter<<<PB, 256, 0, stream>>>(x, ei, nw, T1, NE);
    hipMemsetAsync(T2, 0, FEAT_BYTES, stream);
    prop_scatter<<<PB, 256, 0, stream>>>(T1, ei, nw, T2, NE);
    cheb_mm<64, true><<<(NN + 3) / 4, 256, 0, stream>>>(x, T1, T2, W1, b1, H, NN);

    // ---- layer 2: out = H@W2_0 + T1@W2_1 + (2*T2 - H)@W2_2 + b2 ----
    hipMemsetAsync(T1, 0, FEAT_BYTES, stream);
    prop_scatter<<<PB, 256, 0, stream>>>(H, ei, nw, T1, NE);
    hipMemsetAsync(T2, 0, FEAT_BYTES, stream);
    prop_scatter<<<PB, 256, 0, stream>>>(T1, ei, nw, T2, NE);
    cheb_mm<32, false><<<(NN + 7) / 8, 256, 0, stream>>>(H, T1, T2, W2, b2, out, NN);
}

// Round 3
// 725.902 us; speedup vs baseline: 6.1176x; 6.1176x over previous
//
#include <hip/hip_runtime.h>

#define N_NODES_C 100000
#define N_EDGES_C 1200000

// ---------- degree histogram (int) over row ----------
__global__ void hist_kernel(const int* __restrict__ ei, int* __restrict__ cnt, int nedges) {
    int e = blockIdx.x * blockDim.x + threadIdx.x;
    if (e >= nedges) return;
    atomicAdd(cnt + ei[e], 1);
}

// ---------- deg(int) -> deg_inv_sqrt(float) ----------
__global__ void deg_to_dis(const int* __restrict__ cnt, float* __restrict__ dis, int n) {
    int i = blockIdx.x * blockDim.x + threadIdx.x;
    if (i >= n) return;
    float d = (float)cnt[i];
    dis[i] = (d > 0.f) ? (1.0f / sqrtf(fmaxf(d, 1.f))) : 0.f;
}

// ---------- exclusive scan: stage 1 (1024 elems/block, 256 threads) ----------
__global__ __launch_bounds__(256) void scan1(const int* __restrict__ cnt, int* __restrict__ rowptr,
                                             int* __restrict__ blocksum, int n) {
    __shared__ int s[256];
    int base = blockIdx.x * 1024 + threadIdx.x * 4;
    int v[4];
    int sum = 0;
#pragma unroll
    for (int i = 0; i < 4; ++i) {
        int idx = base + i;
        v[i] = (idx < n) ? cnt[idx] : 0;
        sum += v[i];
    }
    s[threadIdx.x] = sum;
    __syncthreads();
    for (int off = 1; off < 256; off <<= 1) {
        int val = s[threadIdx.x];
        int add = (threadIdx.x >= off) ? s[threadIdx.x - off] : 0;
        __syncthreads();
        s[threadIdx.x] = val + add;
        __syncthreads();
    }
    int run = (threadIdx.x > 0) ? s[threadIdx.x - 1] : 0;
#pragma unroll
    for (int i = 0; i < 4; ++i) {
        int idx = base + i;
        if (idx < n) rowptr[idx] = run;
        run += v[i];
    }
    if (threadIdx.x == 255) blocksum[blockIdx.x] = s[255];
}

// ---------- scan stage 2: serial scan of block sums (nb ~ 98) ----------
__global__ void scan2(int* __restrict__ blocksum, int nb) {
    if (threadIdx.x == 0 && blockIdx.x == 0) {
        int acc = 0;
        for (int i = 0; i < nb; ++i) {
            int t = blocksum[i];
            blocksum[i] = acc;
            acc += t;
        }
    }
}

// ---------- scan stage 3: add block offsets, copy to `next`, cap rowptr ----------
__global__ void scan3(int* __restrict__ rowptr, int* __restrict__ next,
                      const int* __restrict__ blocksum, int n, int nedges) {
    int i = blockIdx.x * blockDim.x + threadIdx.x;
    if (i < n) {
        int v = rowptr[i] + blocksum[i >> 10];
        rowptr[i] = v;
        next[i] = v;
    }
    if (i == n) rowptr[n] = nedges;
}

// ---------- bucket-scatter edges into CSR with fused norm weight ----------
__global__ void edge_scatter(const int* __restrict__ ei, const float* __restrict__ dis,
                             int* __restrict__ next, int2* __restrict__ colw, int nedges) {
    int e = blockIdx.x * blockDim.x + threadIdx.x;
    if (e >= nedges) return;
    int r = ei[e];
    int c = ei[nedges + e];
    float w = -dis[r] * dis[c];
    int pos = atomicAdd(next + r, 1);
    colw[pos] = make_int2(c, __float_as_int(w));
}

// ---------- prop: out[r] = sum_{e in CSR[r]} w_e * t[col_e], one wave/node ----------
__global__ __launch_bounds__(256) void prop_gather(const float* __restrict__ t,
                                                   const int* __restrict__ rowptr,
                                                   const int2* __restrict__ colw,
                                                   float* __restrict__ out, int nnodes) {
    int node = blockIdx.x * 4 + (threadIdx.x >> 6);
    if (node >= nnodes) return;
    int lane = threadIdx.x & 63;
    int s = rowptr[node];
    int e = rowptr[node + 1];
    float acc = 0.f;
    for (int base = s; base < e; base += 64) {
        int m = e - base;
        if (m > 64) m = 64;
        int2 cw = (lane < m) ? colw[base + lane] : make_int2(0, 0);
        for (int j = 0; j < m; ++j) {
            int c = __shfl(cw.x, j);
            float w = __int_as_float(__shfl(cw.y, j));
            acc += w * t[(size_t)c * 64 + lane];
        }
    }
    out[(size_t)node * 64 + lane] = acc;
}

// ---------- fused 3-term matmul: out = Tx0@W0 + Tx1@W1 + (2*t2p - Tx0)@W2 + b ----------
template <int OUTC, bool RELU>
__global__ __launch_bounds__(256) void cheb_mm(const float* __restrict__ t0,
                                               const float* __restrict__ t1,
                                               const float* __restrict__ t2p,
                                               const float* __restrict__ W,  // [3,64,OUTC]
                                               const float* __restrict__ bias,
                                               float* __restrict__ out, int nnodes) {
    constexpr int NPB = 256 / OUTC;   // nodes per iteration
    constexpr int ITERS = 8;          // amortize W staging 8x
    __shared__ float sW[3 * 64 * OUTC];
    __shared__ float s0[NPB][64];
    __shared__ float s1[NPB][64];
    __shared__ float s2[NPB][64];
    int tid = threadIdx.x;
    for (int i = tid; i < 3 * 64 * OUTC; i += 256) sW[i] = W[i];
    int ln = tid / OUTC;
    int c = tid % OUTC;
    float bv = bias[c];
    for (int it = 0; it < ITERS; ++it) {
        int node0 = (blockIdx.x * ITERS + it) * NPB;
        __syncthreads();  // covers sW on first iter, s* reuse after
        for (int i = tid; i < NPB * 64; i += 256) {
            int lnn = i >> 6;
            int k = i & 63;
            int n = node0 + lnn;
            float a0 = 0.f, a1 = 0.f, a2 = 0.f;
            if (n < nnodes) {
                size_t idx = (size_t)n * 64 + k;
                a0 = t0[idx];
                a1 = t1[idx];
                a2 = 2.0f * t2p[idx] - a0;
            }
            s0[lnn][k] = a0;
            s1[lnn][k] = a1;
            s2[lnn][k] = a2;
        }
        __syncthreads();
        int n = node0 + ln;
        if (n >= nnodes) continue;
        float acc = bv;
#pragma unroll
        for (int k = 0; k < 64; ++k) {
            acc += s0[ln][k] * sW[(0 * 64 + k) * OUTC + c];
            acc += s1[ln][k] * sW[(1 * 64 + k) * OUTC + c];
            acc += s2[ln][k] * sW[(2 * 64 + k) * OUTC + c];
        }
        if (RELU) acc = fmaxf(acc, 0.f);
        out[(size_t)n * OUTC + c] = acc;
    }
}

extern "C" void kernel_launch(void* const* d_in, const int* in_sizes, int n_in,
                              void* d_out, int out_size, void* d_ws, size_t ws_size,
                              hipStream_t stream) {
    const float* x  = (const float*)d_in[0];
    const int*   ei = (const int*)d_in[1];   // harness uploads integer inputs as int32
    const float* W1 = (const float*)d_in[2];
    const float* b1 = (const float*)d_in[3];
    const float* W2 = (const float*)d_in[4];
    const float* b2 = (const float*)d_in[5];
    float* out = (float*)d_out;

    const int NN = N_NODES_C;
    const int NE = N_EDGES_C;
    const size_t FEAT_BYTES = (size_t)NN * 64 * sizeof(float);

    char* ws = (char*)d_ws;
    size_t off = 0;
    auto alloc = [&](size_t bytes) -> void* {
        void* p = ws + off;
        off += (bytes + 255) & ~(size_t)255;
        return p;
    };
    int*   cnt      = (int*)alloc((size_t)NN * 4);
    int*   rowptr   = (int*)alloc((size_t)(NN + 1) * 4);
    int*   next     = (int*)alloc((size_t)NN * 4);
    float* dis      = (float*)alloc((size_t)NN * 4);
    int*   blocksum = (int*)alloc(1024);
    int2*  colw     = (int2*)alloc((size_t)NE * 8);
    float* T1       = (float*)alloc(FEAT_BYTES);
    float* T2       = (float*)alloc(FEAT_BYTES);
    float* H        = (float*)alloc(FEAT_BYTES);

    const int EB = (NE + 255) / 256;
    const int NB = (NN + 255) / 256;
    const int SCAN_BLOCKS = (NN + 1023) / 1024;        // 98
    const int PROPB = (NN + 3) / 4;                    // 4 nodes (waves) per block

    // ---- CSR build + normalization ----
    hipMemsetAsync(cnt, 0, (size_t)NN * 4, stream);
    hist_kernel<<<EB, 256, 0, stream>>>(ei, cnt, NE);
    deg_to_dis<<<NB, 256, 0, stream>>>(cnt, dis, NN);
    scan1<<<SCAN_BLOCKS, 256, 0, stream>>>(cnt, rowptr, blocksum, NN);
    scan2<<<1, 64, 0, stream>>>(blocksum, SCAN_BLOCKS);
    scan3<<<(NN + 256) / 256, 256, 0, stream>>>(rowptr, next, blocksum, NN, NE);
    edge_scatter<<<EB, 256, 0, stream>>>(ei, dis, next, colw, NE);

    // ---- layer 1: H = relu(x@W1_0 + T1@W1_1 + (2*T2 - x)@W1_2 + b1) ----
    prop_gather<<<PROPB, 256, 0, stream>>>(x, rowptr, colw, T1, NN);
    prop_gather<<<PROPB, 256, 0, stream>>>(T1, rowptr, colw, T2, NN);
    cheb_mm<64, true><<<(NN + 31) / 32, 256, 0, stream>>>(x, T1, T2, W1, b1, H, NN);

    // ---- layer 2: out = H@W2_0 + T1@W2_1 + (2*T2 - H)@W2_2 + b2 ----
    prop_gather<<<PROPB, 256, 0, stream>>>(H, rowptr, colw, T1, NN);
    prop_gather<<<PROPB, 256, 0, stream>>>(T1, rowptr, colw, T2, NN);
    cheb_mm<32, false><<<(NN + 63) / 64, 256, 0, stream>>>(H, T1, T2, W2, b2, out, NN);
}

// Round 4
// 489.032 us; speedup vs baseline: 9.0807x; 1.4844x over previous
//
#include <hip/hip_runtime.h>

#define N_NODES_C 100000
#define N_EDGES_C 1200000

// ---------- degree histogram (int) over row ----------
__global__ void hist_kernel(const int* __restrict__ ei, int* __restrict__ cnt, int nedges) {
    int e = blockIdx.x * blockDim.x + threadIdx.x;
    if (e >= nedges) return;
    atomicAdd(cnt + ei[e], 1);
}

// ---------- deg(int) -> deg_inv_sqrt(float) ----------
__global__ void deg_to_dis(const int* __restrict__ cnt, float* __restrict__ dis, int n) {
    int i = blockIdx.x * blockDim.x + threadIdx.x;
    if (i >= n) return;
    float d = (float)cnt[i];
    dis[i] = (d > 0.f) ? (1.0f / sqrtf(fmaxf(d, 1.f))) : 0.f;
}

// ---------- exclusive scan: stage 1 (1024 elems/block, 256 threads) ----------
__global__ __launch_bounds__(256) void scan1(const int* __restrict__ cnt, int* __restrict__ rowptr,
                                             int* __restrict__ blocksum, int n) {
    __shared__ int s[256];
    int base = blockIdx.x * 1024 + threadIdx.x * 4;
    int v[4];
    int sum = 0;
#pragma unroll
    for (int i = 0; i < 4; ++i) {
        int idx = base + i;
        v[i] = (idx < n) ? cnt[idx] : 0;
        sum += v[i];
    }
    s[threadIdx.x] = sum;
    __syncthreads();
    for (int off = 1; off < 256; off <<= 1) {
        int val = s[threadIdx.x];
        int add = (threadIdx.x >= off) ? s[threadIdx.x - off] : 0;
        __syncthreads();
        s[threadIdx.x] = val + add;
        __syncthreads();
    }
    int run = (threadIdx.x > 0) ? s[threadIdx.x - 1] : 0;
#pragma unroll
    for (int i = 0; i < 4; ++i) {
        int idx = base + i;
        if (idx < n) rowptr[idx] = run;
        run += v[i];
    }
    if (threadIdx.x == 255) blocksum[blockIdx.x] = s[255];
}

// ---------- scan stage 2: serial scan of block sums (nb ~ 98) ----------
__global__ void scan2(int* __restrict__ blocksum, int nb) {
    if (threadIdx.x == 0 && blockIdx.x == 0) {
        int acc = 0;
        for (int i = 0; i < nb; ++i) {
            int t = blocksum[i];
            blocksum[i] = acc;
            acc += t;
        }
    }
}

// ---------- scan stage 3: add block offsets, copy to `next`, cap rowptr ----------
__global__ void scan3(int* __restrict__ rowptr, int* __restrict__ next,
                      const int* __restrict__ blocksum, int n, int nedges) {
    int i = blockIdx.x * blockDim.x + threadIdx.x;
    if (i < n) {
        int v = rowptr[i] + blocksum[i >> 10];
        rowptr[i] = v;
        next[i] = v;
    }
    if (i == n) rowptr[n] = nedges;
}

// ---------- bucket-scatter edges into CSR with fused norm weight ----------
__global__ void edge_scatter(const int* __restrict__ ei, const float* __restrict__ dis,
                             int* __restrict__ next, int2* __restrict__ colw, int nedges) {
    int e = blockIdx.x * blockDim.x + threadIdx.x;
    if (e >= nedges) return;
    int r = ei[e];
    int c = ei[nedges + e];
    float w = -dis[r] * dis[c];
    int pos = atomicAdd(next + r, 1);
    colw[pos] = make_int2(c, __float_as_int(w));
}

// ---------- fold Chebyshev recurrence into weights ----------
// out = t0@W0 + t1@W1 + (2*prop(t1) - t0)@W2  ==  t0@(W0-W2) + t1@W1 + prop(t1)@(2*W2)
__global__ void fold_w(const float* __restrict__ W, float* __restrict__ Wp, int total) {
    int i = blockIdx.x * blockDim.x + threadIdx.x;
    if (i >= total) return;
    float w0 = W[i], w1 = W[total + i], w2 = W[2 * total + i];
    Wp[i] = w0 - w2;
    Wp[total + i] = w1;
    Wp[2 * total + i] = 2.0f * w2;
}

// ---------- prop: out[r] = sum_e w_e * t[col_e]; 1 wave/node, 4 edges per iter ----------
__global__ __launch_bounds__(256) void prop_gather4(const float* __restrict__ t,
                                                    const int* __restrict__ rowptr,
                                                    const int2* __restrict__ colw,
                                                    float* __restrict__ out, int nnodes) {
    int node = blockIdx.x * 4 + (threadIdx.x >> 6);
    if (node >= nnodes) return;
    int lane = threadIdx.x & 63;
    int g = lane >> 4;    // edge group 0..3
    int gl = lane & 15;   // lane within group: handles channels gl*4..gl*4+3
    int s = rowptr[node];
    int e = rowptr[node + 1];
    float4 acc = make_float4(0.f, 0.f, 0.f, 0.f);
    for (int base = s; base < e; base += 64) {
        int m = e - base;
        if (m > 64) m = 64;
        int2 cw = make_int2(0, 0);
        if (lane < m) cw = colw[base + lane];
        int iters = (m + 3) >> 2;
        for (int it = 0; it < iters; ++it) {
            int j = (it << 2) | g;                       // j>=m lanes hold (0,0) -> w=0, safe
            int c = __shfl(cw.x, j);
            float w = __int_as_float(__shfl(cw.y, j));
            float4 v = ((const float4*)(t + (size_t)c * 64))[gl];
            acc.x += w * v.x;
            acc.y += w * v.y;
            acc.z += w * v.z;
            acc.w += w * v.w;
        }
    }
    // reduce partials across the 4 edge-groups
    acc.x += __shfl_xor(acc.x, 16); acc.y += __shfl_xor(acc.y, 16);
    acc.z += __shfl_xor(acc.z, 16); acc.w += __shfl_xor(acc.w, 16);
    acc.x += __shfl_xor(acc.x, 32); acc.y += __shfl_xor(acc.y, 32);
    acc.z += __shfl_xor(acc.z, 32); acc.w += __shfl_xor(acc.w, 32);
    if (g == 0) ((float4*)(out + (size_t)node * 64))[gl] = acc;
}

// ---------- register-tiled GEMM: out = [A0|A1|A2] @ Wp + bias ----------
// Wp is [192][OUTC] (k-major), A* are [N][64]. 4x4 micro-tile per thread.
template <int OUTC, bool RELU>
__global__ __launch_bounds__(256) void cheb_gemm(const float* __restrict__ A0,
                                                 const float* __restrict__ A1,
                                                 const float* __restrict__ A2,
                                                 const float* __restrict__ Wp,
                                                 const float* __restrict__ bias,
                                                 float* __restrict__ out, int nnodes) {
    constexpr int NODES = 4096 / OUTC;   // 64 (OUTC=64) or 128 (OUTC=32)
    constexpr int NG = NODES / 4;        // 16 or 32 node-groups
    constexpr int S = NODES + 4;         // padded k-major row stride (floats)
    constexpr int F4 = NODES * 16 / 256; // float4 staging loads per thread
    __shared__ float sA[64 * S];

    const int tid = threadIdx.x;
    const int ng = tid % NG;
    const int cg = tid / NG;
    const int node0 = blockIdx.x * NODES;
    const int n_base = node0 + ng * 4;

    float4 bv = *(const float4*)(bias + cg * 4);
    float acc[4][4];
#pragma unroll
    for (int j = 0; j < 4; ++j) {
        acc[j][0] = bv.x; acc[j][1] = bv.y; acc[j][2] = bv.z; acc[j][3] = bv.w;
    }

    const float* Aptr[3] = {A0, A1, A2};
    for (int term = 0; term < 3; ++term) {
        const float* A = Aptr[term];
        __syncthreads();
        // stage A-tile k-major (transposed): sA[k][n] = A[node0+n][k]
#pragma unroll
        for (int i = 0; i < F4; ++i) {
            int f = tid + i * 256;      // f = n*16 + kq, lane-consecutive => coalesced
            int n = f >> 4;
            int kq = f & 15;
            int gn = node0 + n;
            float4 v = (gn < nnodes) ? ((const float4*)(A + (size_t)gn * 64))[kq]
                                     : make_float4(0.f, 0.f, 0.f, 0.f);
            sA[(kq * 4 + 0) * S + n] = v.x;
            sA[(kq * 4 + 1) * S + n] = v.y;
            sA[(kq * 4 + 2) * S + n] = v.z;
            sA[(kq * 4 + 3) * S + n] = v.w;
        }
        __syncthreads();
        const float* Wt = Wp + term * 64 * OUTC;
#pragma unroll 8
        for (int k = 0; k < 64; ++k) {
            float4 a = *(const float4*)(sA + k * S + ng * 4);          // 4 nodes at this k
            float4 b = *(const float4*)(Wt + k * OUTC + cg * 4);       // 4 channels (L1-hot)
            acc[0][0] += a.x * b.x; acc[0][1] += a.x * b.y; acc[0][2] += a.x * b.z; acc[0][3] += a.x * b.w;
            acc[1][0] += a.y * b.x; acc[1][1] += a.y * b.y; acc[1][2] += a.y * b.z; acc[1][3] += a.y * b.w;
            acc[2][0] += a.z * b.x; acc[2][1] += a.z * b.y; acc[2][2] += a.z * b.z; acc[2][3] += a.z * b.w;
            acc[3][0] += a.w * b.x; acc[3][1] += a.w * b.y; acc[3][2] += a.w * b.z; acc[3][3] += a.w * b.w;
        }
    }
#pragma unroll
    for (int j = 0; j < 4; ++j) {
        int n = n_base + j;
        if (n >= nnodes) continue;
        float4 o = make_float4(acc[j][0], acc[j][1], acc[j][2], acc[j][3]);
        if (RELU) {
            o.x = fmaxf(o.x, 0.f); o.y = fmaxf(o.y, 0.f);
            o.z = fmaxf(o.z, 0.f); o.w = fmaxf(o.w, 0.f);
        }
        ((float4*)(out + (size_t)n * OUTC))[cg] = o;
    }
}

extern "C" void kernel_launch(void* const* d_in, const int* in_sizes, int n_in,
                              void* d_out, int out_size, void* d_ws, size_t ws_size,
                              hipStream_t stream) {
    const float* x  = (const float*)d_in[0];
    const int*   ei = (const int*)d_in[1];
    const float* W1 = (const float*)d_in[2];
    const float* b1 = (const float*)d_in[3];
    const float* W2 = (const float*)d_in[4];
    const float* b2 = (const float*)d_in[5];
    float* out = (float*)d_out;

    const int NN = N_NODES_C;
    const int NE = N_EDGES_C;
    const size_t FEAT_BYTES = (size_t)NN * 64 * sizeof(float);

    char* ws = (char*)d_ws;
    size_t off = 0;
    auto alloc = [&](size_t bytes) -> void* {
        void* p = ws + off;
        off += (bytes + 255) & ~(size_t)255;
        return p;
    };
    int*   cnt      = (int*)alloc((size_t)NN * 4);
    int*   rowptr   = (int*)alloc((size_t)(NN + 1) * 4);
    int*   next     = (int*)alloc((size_t)NN * 4);
    float* dis      = (float*)alloc((size_t)NN * 4);
    int*   blocksum = (int*)alloc(1024);
    int2*  colw     = (int2*)alloc((size_t)NE * 8);
    float* T1       = (float*)alloc(FEAT_BYTES);
    float* T2       = (float*)alloc(FEAT_BYTES);
    float* H        = (float*)alloc(FEAT_BYTES);
    float* W1p      = (float*)alloc((size_t)3 * 64 * 64 * 4);
    float* W2p      = (float*)alloc((size_t)3 * 64 * 32 * 4);

    const int EB = (NE + 255) / 256;
    const int NB = (NN + 255) / 256;
    const int SCAN_BLOCKS = (NN + 1023) / 1024;
    const int PROPB = (NN + 3) / 4;

    // ---- CSR build + normalization + weight folding ----
    hipMemsetAsync(cnt, 0, (size_t)NN * 4, stream);
    hist_kernel<<<EB, 256, 0, stream>>>(ei, cnt, NE);
    deg_to_dis<<<NB, 256, 0, stream>>>(cnt, dis, NN);
    scan1<<<SCAN_BLOCKS, 256, 0, stream>>>(cnt, rowptr, blocksum, NN);
    scan2<<<1, 64, 0, stream>>>(blocksum, SCAN_BLOCKS);
    scan3<<<(NN + 256) / 256, 256, 0, stream>>>(rowptr, next, blocksum, NN, NE);
    edge_scatter<<<EB, 256, 0, stream>>>(ei, dis, next, colw, NE);
    fold_w<<<(64 * 64 + 255) / 256, 256, 0, stream>>>(W1, W1p, 64 * 64);
    fold_w<<<(64 * 32 + 255) / 256, 256, 0, stream>>>(W2, W2p, 64 * 32);

    // ---- layer 1: H = relu(x@(W0-W2) + T1@W1 + T2@(2W2) + b1), T2 = prop(T1) raw ----
    prop_gather4<<<PROPB, 256, 0, stream>>>(x, rowptr, colw, T1, NN);
    prop_gather4<<<PROPB, 256, 0, stream>>>(T1, rowptr, colw, T2, NN);
    cheb_gemm<64, true><<<(NN + 63) / 64, 256, 0, stream>>>(x, T1, T2, W1p, b1, H, NN);

    // ---- layer 2 ----
    prop_gather4<<<PROPB, 256, 0, stream>>>(H, rowptr, colw, T1, NN);
    prop_gather4<<<PROPB, 256, 0, stream>>>(T1, rowptr, colw, T2, NN);
    cheb_gemm<32, false><<<(NN + 127) / 128, 256, 0, stream>>>(H, T1, T2, W2p, b2, out, NN);
}

// Round 5
// 443.218 us; speedup vs baseline: 10.0194x; 1.1034x over previous
//
#include <hip/hip_runtime.h>
#include <hip/hip_fp16.h>

#define N_NODES_C 100000
#define N_EDGES_C 1200000

// ---------- degree histogram (int) over row ----------
__global__ void hist_kernel(const int* __restrict__ ei, int* __restrict__ cnt, int nedges) {
    int e = blockIdx.x * blockDim.x + threadIdx.x;
    if (e >= nedges) return;
    atomicAdd(cnt + ei[e], 1);
}

// ---------- deg(int) -> deg_inv_sqrt(float) ----------
__global__ void deg_to_dis(const int* __restrict__ cnt, float* __restrict__ dis, int n) {
    int i = blockIdx.x * blockDim.x + threadIdx.x;
    if (i >= n) return;
    float d = (float)cnt[i];
    dis[i] = (d > 0.f) ? (1.0f / sqrtf(fmaxf(d, 1.f))) : 0.f;
}

// ---------- exclusive scan: stage 1 (1024 elems/block, 256 threads) ----------
__global__ __launch_bounds__(256) void scan1(const int* __restrict__ cnt, int* __restrict__ rowptr,
                                             int* __restrict__ blocksum, int n) {
    __shared__ int s[256];
    int base = blockIdx.x * 1024 + threadIdx.x * 4;
    int v[4];
    int sum = 0;
#pragma unroll
    for (int i = 0; i < 4; ++i) {
        int idx = base + i;
        v[i] = (idx < n) ? cnt[idx] : 0;
        sum += v[i];
    }
    s[threadIdx.x] = sum;
    __syncthreads();
    for (int off = 1; off < 256; off <<= 1) {
        int val = s[threadIdx.x];
        int add = (threadIdx.x >= off) ? s[threadIdx.x - off] : 0;
        __syncthreads();
        s[threadIdx.x] = val + add;
        __syncthreads();
    }
    int run = (threadIdx.x > 0) ? s[threadIdx.x - 1] : 0;
#pragma unroll
    for (int i = 0; i < 4; ++i) {
        int idx = base + i;
        if (idx < n) rowptr[idx] = run;
        run += v[i];
    }
    if (threadIdx.x == 255) blocksum[blockIdx.x] = s[255];
}

// ---------- scan stage 2: serial scan of block sums (nb ~ 98) ----------
__global__ void scan2(int* __restrict__ blocksum, int nb) {
    if (threadIdx.x == 0 && blockIdx.x == 0) {
        int acc = 0;
        for (int i = 0; i < nb; ++i) {
            int t = blocksum[i];
            blocksum[i] = acc;
            acc += t;
        }
    }
}

// ---------- scan stage 3: add block offsets, copy to `next`, cap rowptr ----------
__global__ void scan3(int* __restrict__ rowptr, int* __restrict__ next,
                      const int* __restrict__ blocksum, int n, int nedges) {
    int i = blockIdx.x * blockDim.x + threadIdx.x;
    if (i < n) {
        int v = rowptr[i] + blocksum[i >> 10];
        rowptr[i] = v;
        next[i] = v;
    }
    if (i == n) rowptr[n] = nedges;
}

// ---------- bucket-scatter edges into CSR with fused norm weight ----------
__global__ void edge_scatter(const int* __restrict__ ei, const float* __restrict__ dis,
                             int* __restrict__ next, int2* __restrict__ colw, int nedges) {
    int e = blockIdx.x * blockDim.x + threadIdx.x;
    if (e >= nedges) return;
    int r = ei[e];
    int c = ei[nedges + e];
    float w = -dis[r] * dis[c];
    int pos = atomicAdd(next + r, 1);
    colw[pos] = make_int2(c, __float_as_int(w));
}

// ---------- fold Chebyshev recurrence into weights ----------
__global__ void fold_w(const float* __restrict__ W, float* __restrict__ Wp, int total) {
    int i = blockIdx.x * blockDim.x + threadIdx.x;
    if (i >= total) return;
    float w0 = W[i], w1 = W[total + i], w2 = W[2 * total + i];
    Wp[i] = w0 - w2;
    Wp[total + i] = w1;
    Wp[2 * total + i] = 2.0f * w2;
}

// ---------- fp32 -> fp16 feature conversion (4 elems/thread) ----------
__global__ void f2h_kernel(const float* __restrict__ in, __half* __restrict__ out, int n4) {
    int i = blockIdx.x * blockDim.x + threadIdx.x;
    if (i >= n4) return;
    float4 v = ((const float4*)in)[i];
    __half2 tmp[2];
    tmp[0] = __floats2half2_rn(v.x, v.y);
    tmp[1] = __floats2half2_rn(v.z, v.w);
    ((float2*)out)[i] = *(float2*)tmp;
}

// ---------- prop: out[r] = sum_e w_e * t[col_e]; fp16 rows, 8 lanes/edge ----------
__global__ __launch_bounds__(256) void prop_gather_h(const __half* __restrict__ t,
                                                     const int* __restrict__ rowptr,
                                                     const int2* __restrict__ colw,
                                                     __half* __restrict__ out, int nnodes) {
    int node = blockIdx.x * 4 + (threadIdx.x >> 6);
    if (node >= nnodes) return;
    int lane = threadIdx.x & 63;
    int g = lane >> 3;    // edge group 0..7
    int gl = lane & 7;    // channel octet: channels gl*8 .. gl*8+7
    int s = rowptr[node];
    int e = rowptr[node + 1];
    float acc[8] = {0.f, 0.f, 0.f, 0.f, 0.f, 0.f, 0.f, 0.f};
    for (int base = s; base < e; base += 64) {
        int m = e - base;
        if (m > 64) m = 64;
        int2 cw = (lane < m) ? colw[base + lane] : make_int2(0, 0);
        int iters = (m + 7) >> 3;
        for (int it = 0; it < iters; ++it) {
            int j = (it << 3) | g;                  // j>=m lanes hold (0,0) -> w=0, safe
            int c = __shfl(cw.x, j);
            float w = __int_as_float(__shfl(cw.y, j));
            float4 raw = ((const float4*)(t + (size_t)c * 64))[gl];   // half8 = 16B
            const __half2* hp = (const __half2*)&raw;
            float2 f0 = __half22float2(hp[0]);
            float2 f1 = __half22float2(hp[1]);
            float2 f2 = __half22float2(hp[2]);
            float2 f3 = __half22float2(hp[3]);
            acc[0] += w * f0.x; acc[1] += w * f0.y;
            acc[2] += w * f1.x; acc[3] += w * f1.y;
            acc[4] += w * f2.x; acc[5] += w * f2.y;
            acc[6] += w * f3.x; acc[7] += w * f3.y;
        }
    }
#pragma unroll
    for (int i = 0; i < 8; ++i) {
        acc[i] += __shfl_xor(acc[i], 8);
        acc[i] += __shfl_xor(acc[i], 16);
        acc[i] += __shfl_xor(acc[i], 32);
    }
    if (g == 0) {
        __half2 tmp[4];
        tmp[0] = __floats2half2_rn(acc[0], acc[1]);
        tmp[1] = __floats2half2_rn(acc[2], acc[3]);
        tmp[2] = __floats2half2_rn(acc[4], acc[5]);
        tmp[3] = __floats2half2_rn(acc[6], acc[7]);
        ((float4*)(out + (size_t)node * 64))[gl] = *(float4*)tmp;
    }
}

// ---------- register-tiled GEMM: out = [A0|A1|A2] @ Wp + bias (fp16 A, fp32 acc) ----------
template <int OUTC, bool RELU, bool OUTH>
__global__ __launch_bounds__(256) void cheb_gemm_h(const __half* __restrict__ A0,
                                                   const __half* __restrict__ A1,
                                                   const __half* __restrict__ A2,
                                                   const float* __restrict__ Wp,
                                                   const float* __restrict__ bias,
                                                   void* __restrict__ outv, int nnodes) {
    constexpr int NODES = 4096 / OUTC;   // 64 (OUTC=64) or 128 (OUTC=32)
    constexpr int NG = NODES / 4;
    constexpr int S = NODES + 5;         // S ≡ 1 (mod 4): breaks 8-way staging bank alias
    constexpr int F8 = NODES * 8 / 256;  // half8 staging loads per thread
    __shared__ float sA[64 * S];

    const int tid = threadIdx.x;
    const int ng = tid % NG;
    const int cg = tid / NG;
    const int node0 = blockIdx.x * NODES;
    const int n_base = node0 + ng * 4;

    float4 bv = *(const float4*)(bias + cg * 4);
    float acc[4][4];
#pragma unroll
    for (int j = 0; j < 4; ++j) {
        acc[j][0] = bv.x; acc[j][1] = bv.y; acc[j][2] = bv.z; acc[j][3] = bv.w;
    }

    const __half* Aptr[3] = {A0, A1, A2};
    for (int term = 0; term < 3; ++term) {
        const __half* A = Aptr[term];
        __syncthreads();
        // stage A-tile k-major: sA[k][n] = A[node0+n][k], converting fp16 -> fp32
#pragma unroll
        for (int i = 0; i < F8; ++i) {
            int f = tid + i * 256;
            int n = f >> 3;
            int kc = f & 7;          // half8 chunk: channels kc*8 .. kc*8+7
            int gn = node0 + n;
            float4 raw = make_float4(0.f, 0.f, 0.f, 0.f);
            if (gn < nnodes) raw = ((const float4*)(A + (size_t)gn * 64))[kc];
            const __half2* hp = (const __half2*)&raw;
            float2 f0 = __half22float2(hp[0]);
            float2 f1 = __half22float2(hp[1]);
            float2 f2 = __half22float2(hp[2]);
            float2 f3 = __half22float2(hp[3]);
            sA[(kc * 8 + 0) * S + n] = f0.x;
            sA[(kc * 8 + 1) * S + n] = f0.y;
            sA[(kc * 8 + 2) * S + n] = f1.x;
            sA[(kc * 8 + 3) * S + n] = f1.y;
            sA[(kc * 8 + 4) * S + n] = f2.x;
            sA[(kc * 8 + 5) * S + n] = f2.y;
            sA[(kc * 8 + 6) * S + n] = f3.x;
            sA[(kc * 8 + 7) * S + n] = f3.y;
        }
        __syncthreads();
        const float* Wt = Wp + term * 64 * OUTC;
#pragma unroll 8
        for (int k = 0; k < 64; ++k) {
            float4 a = *(const float4*)(sA + k * S + ng * 4);
            float4 b = *(const float4*)(Wt + k * OUTC + cg * 4);
            acc[0][0] += a.x * b.x; acc[0][1] += a.x * b.y; acc[0][2] += a.x * b.z; acc[0][3] += a.x * b.w;
            acc[1][0] += a.y * b.x; acc[1][1] += a.y * b.y; acc[1][2] += a.y * b.z; acc[1][3] += a.y * b.w;
            acc[2][0] += a.z * b.x; acc[2][1] += a.z * b.y; acc[2][2] += a.z * b.z; acc[2][3] += a.z * b.w;
            acc[3][0] += a.w * b.x; acc[3][1] += a.w * b.y; acc[3][2] += a.w * b.z; acc[3][3] += a.w * b.w;
        }
    }
#pragma unroll
    for (int j = 0; j < 4; ++j) {
        int n = n_base + j;
        if (n >= nnodes) continue;
        float4 o = make_float4(acc[j][0], acc[j][1], acc[j][2], acc[j][3]);
        if (RELU) {
            o.x = fmaxf(o.x, 0.f); o.y = fmaxf(o.y, 0.f);
            o.z = fmaxf(o.z, 0.f); o.w = fmaxf(o.w, 0.f);
        }
        if (OUTH) {
            __half* outh = (__half*)outv;
            __half2 tmp[2];
            tmp[0] = __floats2half2_rn(o.x, o.y);
            tmp[1] = __floats2half2_rn(o.z, o.w);
            ((float2*)(outh + (size_t)n * OUTC))[cg] = *(float2*)tmp;
        } else {
            float* outf = (float*)outv;
            ((float4*)(outf + (size_t)n * OUTC))[cg] = o;
        }
    }
}

extern "C" void kernel_launch(void* const* d_in, const int* in_sizes, int n_in,
                              void* d_out, int out_size, void* d_ws, size_t ws_size,
                              hipStream_t stream) {
    const float* x  = (const float*)d_in[0];
    const int*   ei = (const int*)d_in[1];
    const float* W1 = (const float*)d_in[2];
    const float* b1 = (const float*)d_in[3];
    const float* W2 = (const float*)d_in[4];
    const float* b2 = (const float*)d_in[5];
    float* out = (float*)d_out;

    const int NN = N_NODES_C;
    const int NE = N_EDGES_C;
    const size_t HFEAT_BYTES = (size_t)NN * 64 * sizeof(__half);

    char* ws = (char*)d_ws;
    size_t off = 0;
    auto alloc = [&](size_t bytes) -> void* {
        void* p = ws + off;
        off += (bytes + 255) & ~(size_t)255;
        return p;
    };
    int*    cnt      = (int*)alloc((size_t)NN * 4);
    int*    rowptr   = (int*)alloc((size_t)(NN + 1) * 4);
    int*    next     = (int*)alloc((size_t)NN * 4);
    float*  dis      = (float*)alloc((size_t)NN * 4);
    int*    blocksum = (int*)alloc(1024);
    int2*   colw     = (int2*)alloc((size_t)NE * 8);
    __half* xh       = (__half*)alloc(HFEAT_BYTES);
    __half* T1h      = (__half*)alloc(HFEAT_BYTES);
    __half* T2h      = (__half*)alloc(HFEAT_BYTES);
    __half* Hh       = (__half*)alloc(HFEAT_BYTES);
    float*  W1p      = (float*)alloc((size_t)3 * 64 * 64 * 4);
    float*  W2p      = (float*)alloc((size_t)3 * 64 * 32 * 4);

    const int EB = (NE + 255) / 256;
    const int NB = (NN + 255) / 256;
    const int SCAN_BLOCKS = (NN + 1023) / 1024;
    const int PROPB = (NN + 3) / 4;
    const int CONVB = (NN * 64 / 4 + 255) / 256;

    // ---- CSR build + normalization + weight folding + x->fp16 ----
    hipMemsetAsync(cnt, 0, (size_t)NN * 4, stream);
    hist_kernel<<<EB, 256, 0, stream>>>(ei, cnt, NE);
    deg_to_dis<<<NB, 256, 0, stream>>>(cnt, dis, NN);
    scan1<<<SCAN_BLOCKS, 256, 0, stream>>>(cnt, rowptr, blocksum, NN);
    scan2<<<1, 64, 0, stream>>>(blocksum, SCAN_BLOCKS);
    scan3<<<(NN + 256) / 256, 256, 0, stream>>>(rowptr, next, blocksum, NN, NE);
    edge_scatter<<<EB, 256, 0, stream>>>(ei, dis, next, colw, NE);
    fold_w<<<(64 * 64 + 255) / 256, 256, 0, stream>>>(W1, W1p, 64 * 64);
    fold_w<<<(64 * 32 + 255) / 256, 256, 0, stream>>>(W2, W2p, 64 * 32);
    f2h_kernel<<<CONVB, 256, 0, stream>>>(x, xh, NN * 64 / 4);

    // ---- layer 1: Hh = relu(x@(W0-W2) + T1@W1 + T2@(2W2) + b1), T2 = prop(T1) ----
    prop_gather_h<<<PROPB, 256, 0, stream>>>(xh, rowptr, colw, T1h, NN);
    prop_gather_h<<<PROPB, 256, 0, stream>>>(T1h, rowptr, colw, T2h, NN);
    cheb_gemm_h<64, true, true><<<(NN + 63) / 64, 256, 0, stream>>>(xh, T1h, T2h, W1p, b1, Hh, NN);

    // ---- layer 2 ----
    prop_gather_h<<<PROPB, 256, 0, stream>>>(Hh, rowptr, colw, T1h, NN);
    prop_gather_h<<<PROPB, 256, 0, stream>>>(T1h, rowptr, colw, T2h, NN);
    cheb_gemm_h<32, false, false><<<(NN + 127) / 128, 256, 0, stream>>>(Hh, T1h, T2h, W2p, b2, out, NN);
}